// Round 10
// baseline (412.257 us; speedup 1.0000x reference)
//
#include <hip/hip_runtime.h>
#include <hip/hip_bf16.h>

typedef __attribute__((ext_vector_type(8))) short short8;
typedef __attribute__((ext_vector_type(4))) float floatx4;
typedef __attribute__((ext_vector_type(4))) unsigned uint4v;

#define B_ 8
#define C_IN 256
#define C_OUT 256
#define H_ 128
#define W_ 128
#define S_ 512
#define HW_ (H_*W_)
#define LIN_SCALE 0.04419417382415922f   /* 1/sqrt(512) */
#define CONV_SCALE 0.02083333333333333f  /* 1/sqrt(256*9) */
#define EPS_ 1e-8f

#define XPH 130          /* padded H: rows -1..128 -> 0..129 */
#define XPW 136          /* padded W: cols -1..134 -> 0..135 */
#define TTH 8            /* output tile 8h x 32w = 256 px (full 128B out lines) */
#define TTW 32
#define PH2 10           /* halo patch 10 x 34 */
#define PW2 34
#define NPIX2 (PH2*PW2)  /* 340 live pixels */
#define BITEMS 1536      /* padded to 6 exact 256-thread pieces */
#define BUFSZ (BITEMS*16) /* 24576 B per B LDS buffer */
#define NKB 72           /* 8 ci-chunks * 9 taps */
#define NTHR 256         /* 4 waves: 2(M) x 2(N) */

__device__ __forceinline__ unsigned short f2bf(float f) {
  unsigned u = __builtin_bit_cast(unsigned, f);
  u = (u + 0x7fffu + ((u >> 16) & 1u)) >> 16;
  return (unsigned short)u;
}
__device__ __forceinline__ unsigned pack2(float a, float b) {
  return (unsigned)f2bf(a) | ((unsigned)f2bf(b) << 16);
}
__device__ __forceinline__ void gload16(const void* g, void* l) {
  __builtin_amdgcn_global_load_lds(
      (const __attribute__((address_space(1))) unsigned*)g,
      (__attribute__((address_space(3))) unsigned*)l, 16, 0, 0);
}

// ---------------- kernel 1: style modulation s[b][ci] ----------------
__global__ void k_style(const float* __restrict__ style, const float* __restrict__ mw,
                        const float* __restrict__ mb, float* __restrict__ s) {
  __shared__ float sty[S_];
  const int b = blockIdx.x;
  for (int i = threadIdx.x; i < S_; i += 256) sty[i] = style[b*S_ + i];
  __syncthreads();
  const int ci = threadIdx.x;  // 256 threads
  const float* wr = mw + (size_t)ci*S_;
  float acc = 0.f;
  for (int i = 0; i < S_; ++i) acc += sty[i] * wr[i];
  s[b*C_IN + ci] = acc * LIN_SCALE + mb[ci];
}

// ---------------- kernel 2: demod[b][co] ----------------
__global__ void k_demod(const float* __restrict__ weight, const float* __restrict__ s,
                        float* __restrict__ demod) {
  const int b = blockIdx.x >> 8, co = blockIdx.x & 255;
  const int l = threadIdx.x;  // 64 threads
  const float* wrow = weight + (size_t)co*C_IN*9;
  const float* sb = s + b*C_IN;
  float acc = 0.f;
  for (int idx = l; idx < C_IN*9; idx += 64) {
    float wv = wrow[idx] * sb[idx/9];
    acc += wv*wv;
  }
#pragma unroll
  for (int off = 32; off; off >>= 1) acc += __shfl_down(acc, off, 64);
  if (l == 0) demod[blockIdx.x] = rsqrtf(acc * (CONV_SCALE*CONV_SCALE) + EPS_);
}

// ---------------- kernel 3: pack modulated weights into MFMA A-fragment order ----------------
// layout: frag[((b*72 + kb)*16 + mt)*64 + lane][8] bf16, kb = ci_chunk*9 + tap
// A-frag lane l: co = mt*16 + (l&15), k_in = (l>>4)*8 + j, ci = chunk*32 + k_in
__global__ void k_pack(const float* __restrict__ weight, const float* __restrict__ s,
                       const float* __restrict__ demod, unsigned short* __restrict__ frag) {
  const int bid = blockIdx.x;            // (b*72 + kb)*16 + mt
  const int mt = bid & 15;
  const int kb = (bid >> 4) % NKB;
  const int b  = bid / (NKB*16);
  const int l = threadIdx.x;             // 64 threads
  const int co = mt*16 + (l & 15);
  const int chunk = kb / 9, r = kb % 9;
  const float dm = demod[b*C_OUT + co] * CONV_SCALE;
  const float* sb = s + b*C_IN;
  unsigned v[4];
#pragma unroll
  for (int jj = 0; jj < 4; ++jj) {
    int ci0 = chunk*32 + (l >> 4)*8 + jj*2;
    unsigned lo = f2bf(weight[((size_t)co*C_IN + ci0    )*9 + r] * sb[ci0    ] * dm);
    unsigned hi = f2bf(weight[((size_t)co*C_IN + ci0 + 1)*9 + r] * sb[ci0 + 1] * dm);
    v[jj] = lo | (hi << 16);
  }
  unsigned* dst = (unsigned*)(frag + (size_t)bid*512 + l*8);
  dst[0] = v[0]; dst[1] = v[1]; dst[2] = v[2]; dst[3] = v[3];
}

// ---------------- kernel 3b: zero only the read border of xpad ----------------
__global__ void k_border(unsigned short* __restrict__ xp) {
  const int plane = blockIdx.x;          // b*8 + c, 64 planes
  unsigned short* base = xp + (size_t)plane*XPH*XPW*32;
  const uint4v z = {0u,0u,0u,0u};
  for (int i = threadIdx.x; i < 516; i += 256) {
    int hh, ww;
    if (i < 260) { hh = (i < 130) ? 0 : 129; ww = i % 130; }
    else { int j = i - 260; ww = (j < 128) ? 0 : 129; hh = 1 + (j & 127); }
    uint4v* p = (uint4v*)(base + ((size_t)hh*XPW + ww)*32);
    p[0] = z; p[1] = z; p[2] = z; p[3] = z;
  }
}

// ---------------- kernel 3c: NCHW f32 -> chunk-major padded bf16 ----------------
// xpad[b][c][hh][ww][32ci] bf16, c = ci-chunk (8), hh = h+1, ww = w+1.
__global__ void k_xpose(const float* __restrict__ x, unsigned short* __restrict__ xp) {
  __shared__ __align__(16) unsigned lds32[64*128];   // 32 KB
  const int bid = blockIdx.x;          // 8b * 128h * 2
  const int half = bid & 1, h = (bid >> 1) & 127, b = bid >> 8;
  const int w0 = half*64;
  const int t = threadIdx.x;
  const float* xr = x + (size_t)b*C_IN*HW_ + (size_t)h*W_ + w0;
#pragma unroll
  for (int j = 0; j < 8; ++j) {
    int cp = j*16 + (t >> 4);          // ci-pair 0..127
    int ci = cp*2;
    const float* p0 = xr + (size_t)ci*HW_ + (t & 15)*4;
    floatx4 f0 = *(const floatx4*)p0;
    floatx4 f1 = *(const floatx4*)(p0 + HW_);
    int g = cp >> 2, slot = cp & 3;
#pragma unroll
    for (int k = 0; k < 4; ++k) {
      int px = (t & 15)*4 + k;
      lds32[px*128 + ((g ^ ((px >> 2) & 7)) << 2) + slot] = pack2(f0[k], f1[k]);
    }
  }
  __syncthreads();
#pragma unroll
  for (int i = 0; i < 8; ++i) {
    int item = i*256 + t;
    int px = item >> 5, g = item & 31;       // g = 8-ci group = (c<<2)|sub
    int c = (item >> 2) & 7, sub = item & 3;
    int gs = g ^ ((px >> 2) & 7);
    uint4v v = *(const uint4v*)&lds32[px*128 + (gs << 2)];
    unsigned short* dst = xp +
        (((size_t)(b*8 + c)*XPH + (h + 1))*XPW + (w0 + 1 + px))*32 + sub*8;
    *(uint4v*)dst = v;
  }
}

// ---------------- kernel 4: implicit-GEMM conv ----------------
// block: 128 co (ct half) x (8h x 32w = 256 px), 256 threads, 4 waves 2(M)x2(N)
// wave tile 64co x 128px = 4(m) x 8(n) 16x16 frags; acc = 128 AGPR (caps 2
// waves/SIMD — occupancy is register-bound, so the schedule must win, not TLP).
// A: REGISTERS, pa/pb/pc 2-step-ahead rotation (compiler emits precise vmcnt
//    for reg loads). NOT round-6's failure: B pieces are issued 1/step AFTER
//    that step's A-loads, so every A-wait leaves all B staging in flight
//    (FIFO-audited); no entangled drains.
// B: LDS double-buffer (chunk-level), async gload_lds, pre-swizzled source,
//    linear dest (rule #21). ONE barrier per chunk (buffer swap), vmcnt(8)
//    = the 8 in-flight A prefetches; forces the 6 older B loads complete.
// Barriers: 72 -> 7. Compiler pipelines each 9-step chunk as one region.
__launch_bounds__(NTHR, 2)
__global__ void k_conv(const unsigned short* __restrict__ xpad,
                       const unsigned short* __restrict__ frag,
                       float* __restrict__ out) {
  __shared__ __align__(16) unsigned char sm[2*BUFSZ];   // 49152 B
  unsigned char* b0 = sm;
  unsigned char* b1 = sm + BUFSZ;

  const int work = (blockIdx.x & 7)*128 + (blockIdx.x >> 3);  // XCD x <- batch x
  const int ct = work & 1;
  const int w2 = work >> 1;
  const int sx = w2 & 3, sy = (w2 >> 2) & 15, b = w2 >> 6;
  const int h0 = sy*TTH, w0 = sx*TTW;
  const int tid = threadIdx.x;
  const int lane = tid & 63, wv = tid >> 6;
  const int wm = wv >> 1, wn = wv & 1;
  const int sl = lane >> 4, c15 = lane & 15, wn8 = wn*8;

  // per-wave A base: frag + b,kb=0,mt=ct*8+wm*4, this lane
  const unsigned short* fb = frag + ((size_t)b*NKB*16 + (ct*8 + wm*4))*512
                                  + (size_t)lane*8;

  floatx4 acc[4][8];
#pragma unroll
  for (int m = 0; m < 4; ++m)
#pragma unroll
    for (int n = 0; n < 8; ++n) acc[m][n] = floatx4{0.f, 0.f, 0.f, 0.f};

  auto loadA = [&](short8* dst, int kb) {
    const unsigned short* src = fb + (size_t)kb*8192;
    dst[0] = *(const short8*)(src);
    dst[1] = *(const short8*)(src + 512);
    dst[2] = *(const short8*)(src + 1024);
    dst[3] = *(const short8*)(src + 1536);
  };
  // B piece: 1 gload/thread, linear dest item*16; pad items clamp SOURCE only.
  auto stageBpiece = [&](int cSrc, int piece, unsigned char* bbf) {
    int item = piece*256 + tid;
    int px = item >> 2, q8s = item & 3;
    if (px > NPIX2 - 1) px = NPIX2 - 1;
    int ph = px / PW2, pw = px - ph*PW2;
    int q8 = q8s ^ ((px >> 1) & 3);          // pre-swizzled SOURCE (rule #21)
    const unsigned short* src = xpad +
        (((size_t)(b*8 + cSrc)*XPH + h0 + ph)*XPW + (w0 + pw))*32 + q8*8;
    gload16(src, bbf + item*16);
  };

  auto computeStep = [&](const short8* A, int dh, int dw,
                         const unsigned char* bc) __attribute__((always_inline)) {
    __builtin_amdgcn_s_setprio(1);
#pragma unroll
    for (int n = 0; n < 8; ++n) {
      int nt = wn8 + n;
      int pix = ((nt >> 1) + dh)*PW2 + ((nt & 1)*16 + c15 + dw);
      int addr = pix*64 + ((sl ^ ((pix >> 1) & 3)) << 4);
      short8 bb = *(const short8*)(bc + addr);
      acc[0][n] = __builtin_amdgcn_mfma_f32_16x16x32_bf16(A[0], bb, acc[0][n], 0, 0, 0);
      acc[1][n] = __builtin_amdgcn_mfma_f32_16x16x32_bf16(A[1], bb, acc[1][n], 0, 0, 0);
      acc[2][n] = __builtin_amdgcn_mfma_f32_16x16x32_bf16(A[2], bb, acc[2][n], 0, 0, 0);
      acc[3][n] = __builtin_amdgcn_mfma_f32_16x16x32_bf16(A[3], bb, acc[3][n], 0, 0, 0);
    }
    __builtin_amdgcn_s_setprio(0);
  };

  short8 pa[4], pb[4], pc[4];

#define SBAR0 __builtin_amdgcn_sched_barrier(0)
// step r: prefetch A(kb=K+r+2) into the rot-(r+2) buffer, issue B piece r
// (next chunk), compute with rot-r buffer. 9%3==0 -> same pattern each chunk.
#define STEP(PU, PL, R) do { \
    int kb_ = K + (R) + 2; \
    if (kb_ < NKB) loadA(PL, kb_); \
    if (c < 7 && (R) < 6) stageBpiece(c + 1, (R), bs); \
    computeStep(PU, (R)/3, (R)%3, bc); \
  } while (0)

  // prologue: B(0) 6 pieces, A(0)->pa, A(1)->pb; full drain once.
  for (int i = 0; i < 6; ++i) stageBpiece(0, i, b0);
  loadA(pa, 0);
  loadA(pb, 1);
  SBAR0;
  asm volatile("s_waitcnt vmcnt(0)" ::: "memory");
  __builtin_amdgcn_s_barrier();
  SBAR0;

#pragma unroll 1
  for (int c = 0; c < 8; ++c) {
    const int K = c*9;
    unsigned char* bc = (c & 1) ? b1 : b0;
    unsigned char* bs = (c & 1) ? b0 : b1;
    STEP(pa, pc, 0); STEP(pb, pa, 1); STEP(pc, pb, 2);
    STEP(pa, pc, 3); STEP(pb, pa, 4); STEP(pc, pb, 5);
    STEP(pa, pc, 6); STEP(pb, pa, 7); STEP(pc, pb, 8);
    if (c < 7) {
      // chunk boundary: all waves done reading bc; B(c+1) (older than the 8
      // in-flight A prefetches) forced complete; A prefetches stay in flight.
      SBAR0;
      asm volatile("s_waitcnt vmcnt(8)" ::: "memory");
      __builtin_amdgcn_s_barrier();
      SBAR0;
    }
  }
#undef STEP
#undef SBAR0

  // epilogue: C/D col=lane&15 (pixel w), row=(lane>>4)*4+i (co)
  float* ob = out + ((size_t)b*C_OUT + ct*128)*HW_;
  const int tw = lane & 15, rg = lane >> 4;
#pragma unroll
  for (int m = 0; m < 4; ++m) {
#pragma unroll
    for (int n = 0; n < 8; ++n) {
      int co = (wm*4 + m)*16 + rg*4;
      int nt = wn8 + n;
      int h = h0 + (nt >> 1);
      int w = w0 + (nt & 1)*16 + tw;
      float* p = ob + (size_t)co*HW_ + (size_t)h*W_ + w;
#pragma unroll
      for (int i = 0; i < 4; ++i) p[i*HW_] = acc[m][n][i];
    }
  }
}

extern "C" void kernel_launch(void* const* d_in, const int* in_sizes, int n_in,
                              void* d_out, int out_size, void* d_ws, size_t ws_size,
                              hipStream_t stream) {
  const float* x      = (const float*)d_in[0];
  const float* style  = (const float*)d_in[1];
  const float* weight = (const float*)d_in[2];
  const float* mod_w  = (const float*)d_in[3];
  const float* mod_b  = (const float*)d_in[4];
  float* out = (float*)d_out;
  char* ws = (char*)d_ws;

  float* s     = (float*)ws;                            // 8 KB
  float* demod = (float*)(ws + 8192);                   // 8 KB
  unsigned short* frag = (unsigned short*)(ws + 16384); // 9.44 MB
  unsigned short* xpad = (unsigned short*)(ws + (16u<<20)); // 72.4 MB chunk-major bf16

  k_style<<<B_, 256, 0, stream>>>(style, mod_w, mod_b, s);
  k_demod<<<B_*C_OUT, 64, 0, stream>>>(weight, s, demod);
  k_pack<<<B_*NKB*16, 64, 0, stream>>>(weight, s, demod, frag);
  k_border<<<B_*8, 256, 0, stream>>>(xpad);
  k_xpose<<<B_*H_*2, 256, 0, stream>>>(x, xpad);
  k_conv<<<B_*2*16*4, NTHR, 0, stream>>>(xpad, frag, out);
}